// Round 1
// baseline (59.245 us; speedup 1.0000x reference)
//
#include <hip/hip_runtime.h>

#define N_IMG 8
#define CIN   128
#define H_IN  56
#define W_IN  56
#define COUT  128
#define KTAP  9
#define HW    3136
#define KTOT  1152
#define BM    64
#define APAD  40

typedef __attribute__((ext_vector_type(8))) short short8;
typedef __attribute__((ext_vector_type(4))) float f32x4;

__device__ __forceinline__ unsigned short f2b(float f) {
    unsigned u = __builtin_bit_cast(unsigned, f);
    u = u + 0x7FFFu + ((u >> 16) & 1u);
    return (unsigned short)(u >> 16);
}
__device__ __forceinline__ float b2f(unsigned short h) {
    unsigned u = ((unsigned)h) << 16;
    return __builtin_bit_cast(float, u);
}

// x (N,C,H,W) f32 -> xt (N,H,W,C) bf16
__global__ __launch_bounds__(256) void xpose_kernel(const float* __restrict__ x,
                                                    unsigned short* __restrict__ xt) {
    int tid = threadIdx.x;
    int c = tid & 127;
    int half = tid >> 7;
    int b = blockIdx.x;              // 8*98 = 784 blocks, 32 hw each
    int n = b / 98;
    int hw0 = (b - n * 98) * 32 + half * 16;
    const float* xp = x + ((size_t)(n * CIN + c)) * HW + hw0;
    unsigned short* op = xt + ((size_t)n * HW + hw0) * CIN + c;
#pragma unroll
    for (int r = 0; r < 16; ++r) op[r * CIN] = f2b(xp[r]);
}

// weight (COUT,CIN,3,3) f32 -> wr [COUT][kt*128+c] bf16
__global__ __launch_bounds__(256) void wprep_kernel(const float* __restrict__ w,
                                                    unsigned short* __restrict__ wr) {
    int idx = blockIdx.x * 256 + threadIdx.x;
    if (idx >= COUT * KTOT) return;
    int o = idx / KTOT;
    int r = idx - o * KTOT;
    int kt = r >> 7;
    int c = r & 127;
    wr[idx] = f2b(w[((size_t)o * CIN + c) * KTAP + kt]);
}

__global__ __launch_bounds__(256) void deform_main(
    const float* __restrict__ offset, const float* __restrict__ x2,
    const float* __restrict__ bias, const unsigned short* __restrict__ xt,
    const unsigned short* __restrict__ wr, float* __restrict__ out)
{
    __shared__ int4   lin_lds[576];   // byte offsets of 4 corners, per (tap,pixel)
    __shared__ float4 wt_lds[576];    // 4 bilinear weights (0 when OOB)
    __shared__ short  a_lds[BM * APAD];

    int tid = threadIdx.x;
    int pix0 = blockIdx.x * BM;       // 3136 % 64 == 0 -> one image per WG
    int n = pix0 / HW;
    int hw0 = pix0 - n * HW;

    // ---- per-WG bilinear parameter stage: 576 = 9 taps x 64 pixels ----
    for (int i = tid; i < 9 * BM; i += 256) {
        int tap = i >> 6;
        int pl  = i & 63;
        int hw = hw0 + pl;
        int ho = hw / W_IN;
        int wo = hw - ho * W_IN;
        const float* offp = offset + ((size_t)n * 18 + tap * 2) * HW + hw;
        float offy = offp[0];
        float offx = offp[HW];
        int ki = tap / 3;
        int kj = tap - ki * 3;
        float py = (float)(ho - 1 + ki) + offy;
        float px = (float)(wo - 1 + kj) + offx;
        float y0f = floorf(py), x0f = floorf(px);
        float wy = py - y0f, wx = px - x0f;
        int y0 = (int)y0f, x0 = (int)x0f;
        int y1 = y0 + 1, x1 = x0 + 1;
        bool vy0 = (y0 >= 0) && (y0 < H_IN);
        bool vy1 = (y1 >= 0) && (y1 < H_IN);
        bool vx0 = (x0 >= 0) && (x0 < W_IN);
        bool vx1 = (x1 >= 0) && (x1 < W_IN);
        int cy0 = min(max(y0, 0), H_IN - 1), cy1 = min(max(y1, 0), H_IN - 1);
        int cx0 = min(max(x0, 0), W_IN - 1), cx1 = min(max(x1, 0), W_IN - 1);
        int4 lv;
        lv.x = (cy0 * W_IN + cx0) * (CIN * 2);
        lv.y = (cy0 * W_IN + cx1) * (CIN * 2);
        lv.z = (cy1 * W_IN + cx0) * (CIN * 2);
        lv.w = (cy1 * W_IN + cx1) * (CIN * 2);
        float4 wv;
        wv.x = (vy0 && vx0) ? (1.f - wy) * (1.f - wx) : 0.f;
        wv.y = (vy0 && vx1) ? (1.f - wy) * wx : 0.f;
        wv.z = (vy1 && vx0) ? wy * (1.f - wx) : 0.f;
        wv.w = (vy1 && vx1) ? wy * wx : 0.f;
        lin_lds[i] = lv;
        wt_lds[i] = wv;
    }
    __syncthreads();

    int lane  = tid & 63;
    int wv_id = tid >> 6;     // wave 0..3 -> cout block of 32
    int llo = lane & 15;
    int lhi = lane >> 4;
    int pixel = tid >> 2;     // A-build mapping: 64 pixels x 4 channel groups
    int cg    = tid & 3;
    const unsigned short* xtn = xt + (size_t)n * HW * CIN;

    f32x4 acc[4][2] = {};

    for (int cc = 0; cc < 36; ++cc) {
        int kt = cc >> 2;            // tap
        int c0 = (cc & 3) << 5;      // channel base 0/32/64/96

        // ---- build A tile: 64 pixels x 32 channels (tap kt) ----
        int pi = kt * 64 + pixel;
        int4   lv = lin_lds[pi];
        float4 wv = wt_lds[pi];
        const char* base = (const char*)(xtn + c0 + cg * 8);
        short8 v00 = *(const short8*)(base + lv.x);
        short8 v01 = *(const short8*)(base + lv.y);
        short8 v10 = *(const short8*)(base + lv.z);
        short8 v11 = *(const short8*)(base + lv.w);
        short8 av;
#pragma unroll
        for (int j = 0; j < 8; ++j) {
            float r = wv.x * b2f((unsigned short)v00[j])
                    + wv.y * b2f((unsigned short)v01[j])
                    + wv.z * b2f((unsigned short)v10[j])
                    + wv.w * b2f((unsigned short)v11[j]);
            av[j] = (short)f2b(r);
        }
        *(short8*)&a_lds[pixel * APAD + cg * 8] = av;
        __syncthreads();

        // ---- MFMA: each wave 64 pixels x 32 couts ----
        size_t koff = (size_t)kt * 128 + c0 + lhi * 8;
        short8 b0 = *(const short8*)(wr + ((size_t)(wv_id * 32 + llo)) * KTOT + koff);
        short8 b1 = *(const short8*)(wr + ((size_t)(wv_id * 32 + 16 + llo)) * KTOT + koff);
#pragma unroll
        for (int m = 0; m < 4; ++m) {
            short8 a = *(const short8*)&a_lds[(m * 16 + llo) * APAD + lhi * 8];
            acc[m][0] = __builtin_amdgcn_mfma_f32_16x16x32_bf16(a, b0, acc[m][0], 0, 0, 0);
            acc[m][1] = __builtin_amdgcn_mfma_f32_16x16x32_bf16(a, b1, acc[m][1], 0, 0, 0);
        }
        __syncthreads();
    }

    // ---- epilogue: + bias + x2, ReLU, float4 stores (4 consecutive pixels) ----
    float bv0 = bias[wv_id * 32 + llo];
    float bv1 = bias[wv_id * 32 + 16 + llo];
#pragma unroll
    for (int m = 0; m < 4; ++m) {
        int hw = hw0 + m * 16 + lhi * 4;
#pragma unroll
        for (int nn = 0; nn < 2; ++nn) {
            int cout = wv_id * 32 + nn * 16 + llo;
            size_t off = ((size_t)n * COUT + cout) * HW + hw;
            f32x4 xv = *(const f32x4*)(x2 + off);
            float bb = nn ? bv1 : bv0;
            f32x4 o;
#pragma unroll
            for (int r = 0; r < 4; ++r) {
                float v = acc[m][nn][r] + bb + xv[r];
                o[r] = v > 0.f ? v : 0.f;
            }
            *(f32x4*)(out + off) = o;
        }
    }
}

extern "C" void kernel_launch(void* const* d_in, const int* in_sizes, int n_in,
                              void* d_out, int out_size, void* d_ws, size_t ws_size,
                              hipStream_t stream) {
    const float* x      = (const float*)d_in[0];
    const float* offset = (const float*)d_in[1];
    const float* weight = (const float*)d_in[2];
    const float* bias   = (const float*)d_in[3];
    const float* x2     = (const float*)d_in[4];
    float* out = (float*)d_out;

    const size_t XT_BYTES = (size_t)N_IMG * HW * CIN * 2;   // 6,422,528
    unsigned short* xt = (unsigned short*)d_ws;
    unsigned short* wr = (unsigned short*)((char*)d_ws + XT_BYTES);

    xpose_kernel<<<784, 256, 0, stream>>>(x, xt);
    wprep_kernel<<<(COUT * KTOT + 255) / 256, 256, 0, stream>>>(weight, wr);
    deform_main<<<(N_IMG * HW) / BM, 256, 0, stream>>>(offset, x2, bias, xt, wr, out);
}